// Round 4
// baseline (138.865 us; speedup 1.0000x reference)
//
#include <hip/hip_runtime.h>
#include <hip/hip_fp16.h>
#include <cmath>

// Encoder_conv2: 5-level multires feature encoder, SINGLE fused kernel.
//   Per block: (0) prefetch x/y coords (latency hidden behind prologue)
//              (1) stage raw F tables into LDS as rounded bf16 (31.3 KB)
//              (2) depthwise 3x3 conv + tanh from LDS -> fp16 texel table
//                  in LDS (31.3 KB, [level][cell][y][x][c4], 8B texels)
//              (3) bilinear-sample PPT points/thread, fp32 weighting,
//                  coalesced float4 row stores (80 B rows, 16B aligned).
// LDS total 62.6 KB -> 2 blocks/CU @ 512 thr = 16 waves/CU (measured R2/R3:
// 16 vs 32 waves is neutral, sampler is write/latency bound, not LDS-bw).
// Fusing removes: conv kernel launch + graph gap + table global round-trip.
// bf16 staging adds <= ~1.2e-7 output error; fp16 table adds ~5e-9; observed
// baseline absmax 1.19e-7 vs threshold 5.6e-7 -> ample margin.

#define NTH 512
#define PPT 4   // 489 blocks -> ~1.9 resident rounds at 2 blocks/CU

constexpr int TOT = 15648;      // total table elements (sum 8*r^2)
// per-level element offsets (sizes 8*r^2: 512,1152,3200,2592,8192)
#define OFF0 0
#define OFF1 512
#define OFF2 1664
#define OFF3 4864
#define OFF4 7456

// ---------------- Stage 1: raw F -> rounded bf16 in LDS ---------------------
__device__ __forceinline__ void stage_level(const float* __restrict__ F,
                                            unsigned short* __restrict__ dst,
                                            int n, int tid)
{
    for (int i = tid; i < n; i += NTH) {
        unsigned int u = __float_as_uint(F[i]);
        dst[i] = (unsigned short)((u + 0x8000u) >> 16);   // round-half-up bf16
    }
}

__device__ __forceinline__ float bf16_load(const unsigned short* p)
{
    return __uint_as_float(((unsigned int)*p) << 16);
}

// ---------------- Stage 2: depthwise conv 3x3 (SAME) + tanh -----------------
// i = tid + k*NTH with NTH%4==0  ->  c = i&3 == tid&3 is constant per thread,
// so the 9 weights for this thread's channel live in registers (wreg).
template<int R>
__device__ __forceinline__ void conv_level(const unsigned short* __restrict__ raw,
                                           const float* __restrict__ wreg,
                                           __half* __restrict__ dst, int tid)
{
    const int n = 8 * R * R;              // 2 cells * 4 ch * R * R
    for (int i = tid; i < n; i += NTH) {
        int c    = i & 3;
        int pos  = i >> 2;
        int cell = (pos >= R * R) ? 1 : 0;
        int rem  = pos - cell * R * R;
        int yy   = rem / R;               // R compile-time: magic-mul
        int xx   = rem - yy * R;
        const unsigned short* Fc = raw + (cell * 4 + c) * R * R;
        float acc = 0.f;
#pragma unroll
        for (int ky = 0; ky < 3; ++ky) {
#pragma unroll
            for (int kx = 0; kx < 3; ++kx) {
                int sy = yy + ky - 1, sx = xx + kx - 1;
                if ((unsigned)sy < (unsigned)R && (unsigned)sx < (unsigned)R)
                    acc = fmaf(wreg[ky * 3 + kx], bf16_load(Fc + sy * R + sx), acc);
            }
        }
        dst[cell * (R * R * 4) + (yy * R + xx) * 4 + c] = __float2half(tanhf(acc));
    }
}

// ---------------- Stage 3: bilinear sampling --------------------------------
__device__ __forceinline__ float4 corner_fetch(const __half* __restrict__ p)
{
    uint2 raw = *(const uint2*)p;          // half4 texel, one ds_read_b64
    __half2 lo = *(__half2*)&raw.x;
    __half2 hi = *(__half2*)&raw.y;
    float2 f01 = __half22float2(lo);
    float2 f23 = __half22float2(hi);
    return make_float4(f01.x, f01.y, f23.x, f23.y);
}

template<int R>
__device__ __forceinline__ float4 sample_level(const __half* __restrict__ lt,
                                               float px, float py)
{
    // ix = (gx+1)*0.5*(R-1) with gx = 2x-1  ==  x*(R-1)
    float fx = px * (float)(R - 1);
    float fy = py * (float)(R - 1);
    float4 acc = make_float4(0.f, 0.f, 0.f, 0.f);
#pragma unroll
    for (int cell = 0; cell < 2; ++cell) {
        float ixc = fx + 0.5f * (float)cell;   // off = cell/n_cells
        float iyc = fy + 0.5f * (float)cell;
        float fx0 = floorf(ixc);
        float fy0 = floorf(iyc);
        float wx = ixc - fx0;
        float wy = iyc - fy0;
        int ix0 = (int)fx0;
        int iy0 = (int)fy0;
        int x0 = min(max(ix0,     0), R - 1);
        int x1 = min(max(ix0 + 1, 0), R - 1);
        int y0 = min(max(iy0,     0), R - 1);
        int y1 = min(max(iy0 + 1, 0), R - 1);
        const __half* cb = lt + cell * (R * R * 4);
        float4 nw = corner_fetch(cb + (y0 * R + x0) * 4);
        float4 ne = corner_fetch(cb + (y0 * R + x1) * 4);
        float4 sw = corner_fetch(cb + (y1 * R + x0) * 4);
        float4 se = corner_fetch(cb + (y1 * R + x1) * 4);
        float u = 1.f - wx, v = 1.f - wy;
        float wnw = u * v, wne = wx * v, wsw = u * wy, wse = wx * wy;
        acc.x = fmaf(wnw, nw.x, acc.x); acc.x = fmaf(wne, ne.x, acc.x);
        acc.x = fmaf(wsw, sw.x, acc.x); acc.x = fmaf(wse, se.x, acc.x);
        acc.y = fmaf(wnw, nw.y, acc.y); acc.y = fmaf(wne, ne.y, acc.y);
        acc.y = fmaf(wsw, sw.y, acc.y); acc.y = fmaf(wse, se.y, acc.y);
        acc.z = fmaf(wnw, nw.z, acc.z); acc.z = fmaf(wne, ne.z, acc.z);
        acc.z = fmaf(wsw, sw.z, acc.z); acc.z = fmaf(wse, se.z, acc.z);
        acc.w = fmaf(wnw, nw.w, acc.w); acc.w = fmaf(wne, ne.w, acc.w);
        acc.w = fmaf(wsw, sw.w, acc.w); acc.w = fmaf(wse, se.w, acc.w);
    }
    return acc;
}

__global__ __launch_bounds__(NTH, 4) void fused_kernel(const float* __restrict__ x,
                                                       const float* __restrict__ y,
                                                       const float* __restrict__ F0,
                                                       const float* __restrict__ F1,
                                                       const float* __restrict__ F2,
                                                       const float* __restrict__ F3,
                                                       const float* __restrict__ F4,
                                                       const float* __restrict__ w,
                                                       float* __restrict__ out, int npts)
{
    __shared__ __align__(16) __half        tab[TOT];   // 31,296 B fp16 texels
    __shared__ __align__(16) unsigned short raw[TOT];  // 31,296 B bf16 staged F
    const int tid = threadIdx.x;

    // (0) prefetch x/y — issued before any LDS work so VMEM overlaps prologue
    int p0 = blockIdx.x * (NTH * PPT) + tid;
    float pxs[PPT], pys[PPT];
#pragma unroll
    for (int k = 0; k < PPT; ++k) {
        int p = p0 + k * NTH;
        int pc = (p < npts) ? p : 0;
        pxs[k] = x[pc];
        pys[k] = y[pc];
    }
    // per-thread conv weights: c = tid&3 is this thread's channel for every i
    float wreg[9];
    {
        const float* wc = w + (tid & 3) * 9;
#pragma unroll
        for (int j = 0; j < 9; ++j) wreg[j] = wc[j];
    }

    // (1) stage raw F as rounded bf16
    stage_level(F0, raw + OFF0,  512, tid);
    stage_level(F1, raw + OFF1, 1152, tid);
    stage_level(F2, raw + OFF2, 3200, tid);
    stage_level(F3, raw + OFF3, 2592, tid);
    stage_level(F4, raw + OFF4, 8192, tid);
    __syncthreads();

    // (2) conv -> fp16 texel table
    conv_level<8 >(raw + OFF0, wreg, tab + OFF0, tid);
    conv_level<12>(raw + OFF1, wreg, tab + OFF1, tid);
    conv_level<20>(raw + OFF2, wreg, tab + OFF2, tid);
    conv_level<18>(raw + OFF3, wreg, tab + OFF3, tid);
    conv_level<32>(raw + OFF4, wreg, tab + OFF4, tid);
    __syncthreads();

    // (3) sample
#pragma unroll
    for (int k = 0; k < PPT; ++k) {
        int p = p0 + k * NTH;
        if (p >= npts) continue;
        float px = pxs[k];
        float py = pys[k];
        float4* op = (float4*)(out + (size_t)p * 20);  // 80 B rows, 16B aligned
        op[0] = sample_level<8 >(tab + OFF0, px, py);
        op[1] = sample_level<12>(tab + OFF1, px, py);
        op[2] = sample_level<20>(tab + OFF2, px, py);
        op[3] = sample_level<18>(tab + OFF3, px, py);
        op[4] = sample_level<32>(tab + OFF4, px, py);
    }
}

extern "C" void kernel_launch(void* const* d_in, const int* in_sizes, int n_in,
                              void* d_out, int out_size, void* d_ws, size_t ws_size,
                              hipStream_t stream)
{
    const float* x  = (const float*)d_in[0];
    const float* y  = (const float*)d_in[1];
    const float* w  = (const float*)d_in[2];
    const float* F0 = (const float*)d_in[3];
    const float* F1 = (const float*)d_in[4];
    const float* F2 = (const float*)d_in[5];
    const float* F3 = (const float*)d_in[6];
    const float* F4 = (const float*)d_in[7];
    float* out = (float*)d_out;
    int npts = in_sizes[0];

    int nb = (npts + NTH * PPT - 1) / (NTH * PPT);
    fused_kernel<<<nb, NTH, 0, stream>>>(x, y, F0, F1, F2, F3, F4, w, out, npts);
}

// Round 5
// 126.380 us; speedup vs baseline: 1.0988x; 1.0988x over previous
//
#include <hip/hip_runtime.h>
#include <hip/hip_fp16.h>
#include <cmath>

// Encoder_conv2: 5-level multires feature encoder.
//   Kernel A (tiny): depthwise 3x3 conv + tanh -> PADDED fp16 texel table in
//     d_ws. Layout per level: [cell][y][x][c4], dims (R+1)x(R+1) with last
//     row/col duplicated. Padding makes bilinear cornering clamp-free.
//   Kernel B: stage table to LDS (34.3 KB -> 4 blocks/CU @512thr), bilinear
//     sample 1e6 points. Per cell-level: ONE vaddr, two ds_read2_b64
//     (corner pairs {x0,x0+1} on rows y0,y0+1) -> 2 LDS instr for 4 texels,
//     zero clamps/selects. fp32 weighting, float4 row stores (80 B rows).
//
// R5 rationale: R4 counters showed 1.44 TB/s (18% peak) -> not HBM-bound;
// R2/R3 showed occupancy + read width neutral -> per-point issue/addr/clamp
// overhead around the 40 gathers is the suspect. This halves LDS issue slots
// (40->20) and removes ~40% of per-point VALU. Fusion regressed (R4): split.

#define NTH 512
#define PPT 2   // 977 blocks, 4 blocks/CU resident

// padded per-level sizes: 8*(R+1)^2 elements (2 cells * 4 ch * (R+1)^2)
// RES = [8,12,20,18,32] -> 648,1352,3528,2888,8712 ; total 17128 el = 34256 B
constexpr int PTOT = 17128;
#define OFF0 0
#define OFF1 648
#define OFF2 2000
#define OFF3 5528
#define OFF4 8416

// ---------------- Kernel A: conv 3x3 (SAME) + tanh -> padded fp16 table ----
template<int R>
__device__ __forceinline__ void conv_level(const float* __restrict__ F,
                                           const float* __restrict__ w,
                                           __half* __restrict__ dst,
                                           int tid, int nth)
{
    constexpr int P = R + 1;
    const int n = 8 * P * P;
    for (int i = tid; i < n; i += nth) {
        int c    = i & 3;
        int pos  = i >> 2;
        int cell = (pos >= P * P) ? 1 : 0;
        int rem  = pos - cell * P * P;
        int py   = rem / P;               // P compile-time: magic-mul
        int px   = rem - py * P;
        int yy   = min(py, R - 1);        // duplicate last row/col (padding)
        int xx   = min(px, R - 1);
        const float* Fc = F + (cell * 4 + c) * R * R;
        float acc = 0.f;
#pragma unroll
        for (int ky = 0; ky < 3; ++ky) {
#pragma unroll
            for (int kx = 0; kx < 3; ++kx) {
                int sy = yy + ky - 1, sx = xx + kx - 1;
                if ((unsigned)sy < (unsigned)R && (unsigned)sx < (unsigned)R)
                    acc = fmaf(w[c * 9 + ky * 3 + kx], Fc[sy * R + sx], acc);
            }
        }
        dst[(cell * P * P + py * P + px) * 4 + c] = __float2half(tanhf(acc));
    }
}

__global__ void conv_kernel(const float* __restrict__ F0, const float* __restrict__ F1,
                            const float* __restrict__ F2, const float* __restrict__ F3,
                            const float* __restrict__ F4, const float* __restrict__ w,
                            __half* __restrict__ tab)
{
    int tid = blockIdx.x * blockDim.x + threadIdx.x;
    int nth = gridDim.x * blockDim.x;
    conv_level<8 >(F0, w, tab + OFF0, tid, nth);
    conv_level<12>(F1, w, tab + OFF1, tid, nth);
    conv_level<20>(F2, w, tab + OFF2, tid, nth);
    conv_level<18>(F3, w, tab + OFF3, tid, nth);
    conv_level<32>(F4, w, tab + OFF4, tid, nth);
}

// ---------------- Kernel B: bilinear sampling -------------------------------
__device__ __forceinline__ float4 cvt4(uint2 raw)
{
    __half2 lo = *(__half2*)&raw.x;
    __half2 hi = *(__half2*)&raw.y;
    float2 f01 = __half22float2(lo);
    float2 f23 = __half22float2(hi);
    return make_float4(f01.x, f01.y, f23.x, f23.y);
}

template<int R>
__device__ __forceinline__ float4 sample_level(const __half* __restrict__ lt,
                                               float px, float py)
{
    constexpr int P = R + 1;
    // ix = (gx+1)*0.5*(R-1) with gx = 2x-1  ==  x*(R-1); px,py in [0,1]
    float fx = px * (float)(R - 1);
    float fy = py * (float)(R - 1);
    float4 acc = make_float4(0.f, 0.f, 0.f, 0.f);
#pragma unroll
    for (int cell = 0; cell < 2; ++cell) {
        float ixc = fx + 0.5f * (float)cell;   // off = cell/n_cells
        float iyc = fy + 0.5f * (float)cell;
        float fx0 = floorf(ixc);
        float fy0 = floorf(iyc);
        float wx = ixc - fx0;
        float wy = iyc - fy0;
        int ix0 = (int)fx0;                    // in [0, R-1]; pad handles +1
        int iy0 = (int)fy0;
        const __half* base = lt + (size_t)(cell * P * P + iy0 * P + ix0) * 4;
        // corner pairs: DS-combiner merges each row pair into ds_read2_b64
        uint2 t00 = *(const uint2*)(base);
        uint2 t01 = *(const uint2*)(base + 4);
        uint2 t10 = *(const uint2*)(base + P * 4);
        uint2 t11 = *(const uint2*)(base + P * 4 + 4);
        float4 nw = cvt4(t00), ne = cvt4(t01), sw = cvt4(t10), se = cvt4(t11);
        float u = 1.f - wx, v = 1.f - wy;
        float wnw = u * v, wne = wx * v, wsw = u * wy, wse = wx * wy;
        acc.x = fmaf(wnw, nw.x, acc.x); acc.x = fmaf(wne, ne.x, acc.x);
        acc.x = fmaf(wsw, sw.x, acc.x); acc.x = fmaf(wse, se.x, acc.x);
        acc.y = fmaf(wnw, nw.y, acc.y); acc.y = fmaf(wne, ne.y, acc.y);
        acc.y = fmaf(wsw, sw.y, acc.y); acc.y = fmaf(wse, se.y, acc.y);
        acc.z = fmaf(wnw, nw.z, acc.z); acc.z = fmaf(wne, ne.z, acc.z);
        acc.z = fmaf(wsw, sw.z, acc.z); acc.z = fmaf(wse, se.z, acc.z);
        acc.w = fmaf(wnw, nw.w, acc.w); acc.w = fmaf(wne, ne.w, acc.w);
        acc.w = fmaf(wsw, sw.w, acc.w); acc.w = fmaf(wse, se.w, acc.w);
    }
    return acc;
}

__device__ __forceinline__ void sample_body(const __half* lds,
                                            const float* __restrict__ x,
                                            const float* __restrict__ y,
                                            float* __restrict__ out, int npts)
{
    int p0 = blockIdx.x * (NTH * PPT) + threadIdx.x;
    float pxs[PPT], pys[PPT];
#pragma unroll
    for (int k = 0; k < PPT; ++k) {
        int p = p0 + k * NTH;
        int pc = (p < npts) ? p : 0;
        pxs[k] = x[pc];
        pys[k] = y[pc];
    }
#pragma unroll
    for (int k = 0; k < PPT; ++k) {
        int p = p0 + k * NTH;
        if (p >= npts) continue;
        float px = pxs[k];
        float py = pys[k];
        // out row = 20 floats (80 B) -> 16B aligned for every p.
        // Store per level to cap VGPR live range (bounds(512,8) -> <=64 VGPR).
        float4* op = (float4*)(out + (size_t)p * 20);
        op[0] = sample_level<8 >(lds + OFF0, px, py);
        op[1] = sample_level<12>(lds + OFF1, px, py);
        op[2] = sample_level<20>(lds + OFF2, px, py);
        op[3] = sample_level<18>(lds + OFF3, px, py);
        op[4] = sample_level<32>(lds + OFF4, px, py);
    }
}

__global__ __launch_bounds__(NTH, 8) void sample_kernel(const float* __restrict__ x,
                                                        const float* __restrict__ y,
                                                        const __half* __restrict__ tab,
                                                        float* __restrict__ out, int npts)
{
    __shared__ __align__(16) __half lds[PTOT];   // 34,256 B -> 4 blocks/CU
    const uint4* g4 = (const uint4*)tab;
    uint4* l4 = (uint4*)lds;
    for (int i = threadIdx.x; i < PTOT * 2 / 16; i += NTH)
        l4[i] = g4[i];
    __syncthreads();
    sample_body(lds, x, y, out, npts);
}

// Fallback if workspace is too small: conv recomputed per block into LDS.
__global__ __launch_bounds__(NTH, 4) void fused_kernel(const float* __restrict__ x,
                                                       const float* __restrict__ y,
                                                       const float* __restrict__ F0,
                                                       const float* __restrict__ F1,
                                                       const float* __restrict__ F2,
                                                       const float* __restrict__ F3,
                                                       const float* __restrict__ F4,
                                                       const float* __restrict__ w,
                                                       float* __restrict__ out, int npts)
{
    __shared__ __align__(16) __half lds[PTOT];
    conv_level<8 >(F0, w, lds + OFF0, threadIdx.x, NTH);
    conv_level<12>(F1, w, lds + OFF1, threadIdx.x, NTH);
    conv_level<20>(F2, w, lds + OFF2, threadIdx.x, NTH);
    conv_level<18>(F3, w, lds + OFF3, threadIdx.x, NTH);
    conv_level<32>(F4, w, lds + OFF4, threadIdx.x, NTH);
    __syncthreads();
    sample_body(lds, x, y, out, npts);
}

extern "C" void kernel_launch(void* const* d_in, const int* in_sizes, int n_in,
                              void* d_out, int out_size, void* d_ws, size_t ws_size,
                              hipStream_t stream)
{
    const float* x  = (const float*)d_in[0];
    const float* y  = (const float*)d_in[1];
    const float* w  = (const float*)d_in[2];
    const float* F0 = (const float*)d_in[3];
    const float* F1 = (const float*)d_in[4];
    const float* F2 = (const float*)d_in[5];
    const float* F3 = (const float*)d_in[6];
    const float* F4 = (const float*)d_in[7];
    float* out = (float*)d_out;
    int npts = in_sizes[0];

    int nb = (npts + NTH * PPT - 1) / (NTH * PPT);

    if (ws_size >= (size_t)PTOT * sizeof(__half)) {
        __half* tab = (__half*)d_ws;
        conv_kernel<<<(PTOT + 255) / 256, 256, 0, stream>>>(F0, F1, F2, F3, F4, w, tab);
        sample_kernel<<<nb, NTH, 0, stream>>>(x, y, tab, out, npts);
    } else {
        fused_kernel<<<nb, NTH, 0, stream>>>(x, y, F0, F1, F2, F3, F4, w, out, npts);
    }
}